// Round 1
// baseline (3023.559 us; speedup 1.0000x reference)
//
#include <hip/hip_runtime.h>
#include <stdint.h>

#define NB 512   // batch
#define NN 128   // nodes
#define NT 336   // timesteps
#define NH 32    // hidden
#define NG 128   // 4*H

typedef short bf16x8 __attribute__((ext_vector_type(8)));
typedef float f32x4  __attribute__((ext_vector_type(4)));

__device__ __forceinline__ float rcp_f(float x) { return __builtin_amdgcn_rcpf(x); }
__device__ __forceinline__ float sigm(float x) {
  return rcp_f(1.0f + exp2f(-1.4426950408889634f * x));
}
__device__ __forceinline__ float tanh_f(float x) {
  return 1.0f - 2.0f * rcp_f(1.0f + exp2f(2.8853900817779268f * x));
}
// float -> bf16 round-to-nearest-even (finite inputs only)
__device__ __forceinline__ short f2bf(float f) {
  unsigned u = __builtin_bit_cast(unsigned, f);
  u += 0x7fffu + ((u >> 16) & 1u);
  return (short)(u >> 16);
}

// One wave handles (node n, 16 batch rows). Block = 4 waves = 64 rows of one node.
// Grid = 128 nodes * 8 row-groups = 1024 blocks.
__global__ __launch_bounds__(256, 2) void lstm_kernel(
    const float* __restrict__ x,
    const float* __restrict__ Wih0,
    const float* __restrict__ Whh0,
    const float* __restrict__ b0,
    const float* __restrict__ Wih1,
    const float* __restrict__ Whh1,
    const float* __restrict__ b1,
    const float* __restrict__ Wfc,
    const float* __restrict__ bfc,
    float* __restrict__ out)
{
  const int tid  = threadIdx.x;
  const int wave = tid >> 6;
  const int lane = tid & 63;
  const int c    = lane & 15;   // tile column (gate-within-tile / A-row)
  const int q    = lane >> 4;   // quad
  const int n    = blockIdx.x >> 3;
  const int m0   = ((blockIdx.x & 7) * 4 + wave) * 16;  // batch row base of this wave

  // Per-wave private scratch: 2 buffers of 16 rows x 40 bf16 (stride 40 -> 80B rows,
  // 16B-aligned b128 reads, 4-way-max write conflicts). No cross-wave sharing -> no barriers.
  __shared__ short lds[4 * 2 * 16 * 40];
  short* my0 = lds + wave * (2 * 16 * 40);
  short* my1 = my0 + 16 * 40;

  // ---- Load weight B-fragments (held in registers for the whole T loop) ----
  // B-frag (K x N = 32 x 16): lane holds B[k = q*8+j][nn = c] = W[g0+c][q*8+j]
  bf16x8 wb0[8], wb1[8], wb2[8];
  {
    const float* pW0 = Whh0 + n * (NG * NH);
    const float* pW1 = Wih1 + n * (NG * NH);
    const float* pW2 = Whh1 + n * (NG * NH);
#pragma unroll
    for (int tau = 0; tau < 8; ++tau) {
      int off = (tau * 16 + c) * NH + q * 8;
#pragma unroll
      for (int j = 0; j < 8; ++j) {
        wb0[tau][j] = f2bf(pW0[off + j]);
        wb1[tau][j] = f2bf(pW1[off + j]);
        wb2[tau][j] = f2bf(pW2[off + j]);
      }
    }
  }
  // Per-lane gate constants: g = tau*16 + c
  float b0g[8], b1g[8], wi0g[8];
#pragma unroll
  for (int tau = 0; tau < 8; ++tau) {
    int g = tau * 16 + c;
    b0g[tau]  = b0[n * NG + g];
    b1g[tau]  = b1[n * NG + g];
    wi0g[tau] = Wih0[n * NG + g];   // W_ih0[n, g, 0]
  }
  const float wfc0 = Wfc[n * NH + c];
  const float wfc1 = Wfc[n * NH + 16 + c];

  // x row pointers for the 4 batch rows this lane's quad covers (m = q*4 + r)
  const float* px0 = x + ((size_t)(m0 + q * 4 + 0) * NN + n) * NT;
  const float* px1 = x + ((size_t)(m0 + q * 4 + 1) * NN + n) * NT;
  const float* px2 = x + ((size_t)(m0 + q * 4 + 2) * NN + n) * NT;
  const float* px3 = x + ((size_t)(m0 + q * 4 + 3) * NN + n) * NT;

  // Recurrent state. a0/a1: A-frags of h0/h1 (bf16). c0v/c1v: cell state in C-layout.
  bf16x8 a0 = {0,0,0,0,0,0,0,0};
  bf16x8 a1 = {0,0,0,0,0,0,0,0};
  f32x4 c0v[2], c1v[2];
#pragma unroll
  for (int tu = 0; tu < 2; ++tu)
#pragma unroll
    for (int r = 0; r < 4; ++r) { c0v[tu][r] = 0.f; c1v[tu][r] = 0.f; }
  float h1l[2][4];  // fp32 h1 of the most recent step (for the final projection)

#pragma unroll 1
  for (int t = 0; t < NT; ++t) {
    float xv0 = px0[t], xv1 = px1[t], xv2 = px2[t], xv3 = px3[t];

    // ---- Layer 0: gates = (x*Wi0 + b0) + h0_prev @ W_hh0^T ----
    f32x4 acc[8];
#pragma unroll
    for (int tau = 0; tau < 8; ++tau) {
      acc[tau][0] = fmaf(xv0, wi0g[tau], b0g[tau]);
      acc[tau][1] = fmaf(xv1, wi0g[tau], b0g[tau]);
      acc[tau][2] = fmaf(xv2, wi0g[tau], b0g[tau]);
      acc[tau][3] = fmaf(xv3, wi0g[tau], b0g[tau]);
    }
#pragma unroll
    for (int tau = 0; tau < 8; ++tau)
      acc[tau] = __builtin_amdgcn_mfma_f32_16x16x32_bf16(a0, wb0[tau], acc[tau], 0, 0, 0);

    // cell update: unit j = tu*16 + c lives at tiles {tu, tu+2, tu+4, tu+6} = {i,f,g,o}
#pragma unroll
    for (int tu = 0; tu < 2; ++tu) {
#pragma unroll
      for (int r = 0; r < 4; ++r) {
        float gi = acc[tu][r], gf = acc[tu+2][r], gg = acc[tu+4][r], go = acc[tu+6][r];
        float cc = sigm(gf) * c0v[tu][r] + sigm(gi) * tanh_f(gg);
        c0v[tu][r] = cc;
        float hh = sigm(go) * tanh_f(cc);
        my0[(q * 4 + r) * 40 + tu * 16 + c] = f2bf(hh);  // row m, col j
      }
    }
    asm volatile("" ::: "memory");
    a0 = *(const bf16x8*)(my0 + c * 40 + q * 8);  // A-frag: A[m=c][k=q*8+j]

    // ---- Layer 1: gates = b1 + h0_new @ W_ih1^T + h1_prev @ W_hh1^T ----
#pragma unroll
    for (int tau = 0; tau < 8; ++tau) {
      acc[tau][0] = b1g[tau]; acc[tau][1] = b1g[tau];
      acc[tau][2] = b1g[tau]; acc[tau][3] = b1g[tau];
    }
#pragma unroll
    for (int tau = 0; tau < 8; ++tau)
      acc[tau] = __builtin_amdgcn_mfma_f32_16x16x32_bf16(a0, wb1[tau], acc[tau], 0, 0, 0);
#pragma unroll
    for (int tau = 0; tau < 8; ++tau)
      acc[tau] = __builtin_amdgcn_mfma_f32_16x16x32_bf16(a1, wb2[tau], acc[tau], 0, 0, 0);

#pragma unroll
    for (int tu = 0; tu < 2; ++tu) {
#pragma unroll
      for (int r = 0; r < 4; ++r) {
        float gi = acc[tu][r], gf = acc[tu+2][r], gg = acc[tu+4][r], go = acc[tu+6][r];
        float cc = sigm(gf) * c1v[tu][r] + sigm(gi) * tanh_f(gg);
        c1v[tu][r] = cc;
        float hh = sigm(go) * tanh_f(cc);
        h1l[tu][r] = hh;
        my1[(q * 4 + r) * 40 + tu * 16 + c] = f2bf(hh);
      }
    }
    asm volatile("" ::: "memory");
    a1 = *(const bf16x8*)(my1 + c * 40 + q * 8);
  }

  // ---- Output: out[b, n] = sum_j h1[b][j] * Wfc[n, 0, j] + bfc[n] ----
  // lane holds h1[m=q*4+r][j=tu*16+c]; reduce over the 16 c-lanes of each quad.
  float s0 = h1l[0][0] * wfc0 + h1l[1][0] * wfc1;
  float s1 = h1l[0][1] * wfc0 + h1l[1][1] * wfc1;
  float s2 = h1l[0][2] * wfc0 + h1l[1][2] * wfc1;
  float s3 = h1l[0][3] * wfc0 + h1l[1][3] * wfc1;
#pragma unroll
  for (int off = 1; off < 16; off <<= 1) {
    s0 += __shfl_xor(s0, off, 64);
    s1 += __shfl_xor(s1, off, 64);
    s2 += __shfl_xor(s2, off, 64);
    s3 += __shfl_xor(s3, off, 64);
  }
  if (c < 4) {
    float v = (c == 0) ? s0 : (c == 1) ? s1 : (c == 2) ? s2 : s3;
    out[(size_t)(m0 + q * 4 + c) * NN + n] = v + bfc[n];
  }
}

extern "C" void kernel_launch(void* const* d_in, const int* in_sizes, int n_in,
                              void* d_out, int out_size, void* d_ws, size_t ws_size,
                              hipStream_t stream) {
  const float* x    = (const float*)d_in[0];
  const float* Wih0 = (const float*)d_in[1];
  const float* Whh0 = (const float*)d_in[2];
  const float* b0   = (const float*)d_in[3];
  const float* Wih1 = (const float*)d_in[4];
  const float* Whh1 = (const float*)d_in[5];
  const float* b1   = (const float*)d_in[6];
  const float* Wfc  = (const float*)d_in[7];
  const float* bfc  = (const float*)d_in[8];
  float* out = (float*)d_out;

  lstm_kernel<<<dim3(1024), dim3(256), 0, stream>>>(
      x, Wih0, Whh0, b0, Wih1, Whh1, b1, Wfc, bfc, out);
}

// Round 3
// 1461.415 us; speedup vs baseline: 2.0689x; 2.0689x over previous
//
#include <hip/hip_runtime.h>
#include <stdint.h>

#define NB 512   // batch
#define NN 128   // nodes
#define NT 336   // timesteps
#define NH 32    // hidden
#define NG 128   // 4*H

typedef short bf16x8 __attribute__((ext_vector_type(8)));
typedef float f32x4  __attribute__((ext_vector_type(4)));
typedef float f32x2  __attribute__((ext_vector_type(2)));
typedef float f32v4  __attribute__((ext_vector_type(4)));

#define LOG2E 1.4426950408889634f

__device__ __forceinline__ f32x2 exp2v(f32x2 v) {
  f32x2 r; r.x = __builtin_amdgcn_exp2f(v.x); r.y = __builtin_amdgcn_exp2f(v.y); return r;
}
__device__ __forceinline__ f32x2 rcpv(f32x2 v) {
  f32x2 r; r.x = __builtin_amdgcn_rcpf(v.x); r.y = __builtin_amdgcn_rcpf(v.y); return r;
}
// gpre = -log2e * gate  (scale folded into weights)
__device__ __forceinline__ f32x2 sigm2(f32x2 gpre) {
  return rcpv(exp2v(gpre) + 1.0f);
}
// gpre = 2*log2e * gate (scale folded into weights)
__device__ __forceinline__ f32x2 tanh2pre(f32x2 gpre) {
  return rcpv(exp2v(gpre) + 1.0f) * (-2.0f) + 1.0f;
}
// float -> bf16 RNE: bfe + add3 + lshr = 3 VALU
__device__ __forceinline__ short f2bf(float f) {
  unsigned u = __builtin_bit_cast(unsigned, f);
  unsigned odd = (u >> 16) & 1u;
  u = u + 0x7fffu + odd;
  return (short)(u >> 16);
}

// One wave handles (node n, 16 batch rows). Block = 4 waves = 64 rows of one node.
// Grid = 128 nodes * 8 row-groups = 1024 blocks.
__global__ __launch_bounds__(256, 2) void lstm_kernel(
    const float* __restrict__ x,
    const float* __restrict__ Wih0,
    const float* __restrict__ Whh0,
    const float* __restrict__ b0,
    const float* __restrict__ Wih1,
    const float* __restrict__ Whh1,
    const float* __restrict__ b1,
    const float* __restrict__ Wfc,
    const float* __restrict__ bfc,
    float* __restrict__ out)
{
  const int tid  = threadIdx.x;
  const int wave = tid >> 6;
  const int lane = tid & 63;
  const int c    = lane & 15;   // tile column (gate-within-tile / A-row)
  const int q    = lane >> 4;   // quad
  const int n    = blockIdx.x >> 3;
  const int m0   = ((blockIdx.x & 7) * 4 + wave) * 16;  // batch row base of this wave

  // Per-wave private LDS: 2 buffers of 16 rows x 40 bf16 (stride 40 -> 80B rows,
  // 16B-aligned b128 reads). No cross-wave sharing -> no barriers.
  __shared__ short lds[4 * 2 * 16 * 40];
  short* my0 = lds + wave * (2 * 16 * 40);
  short* my1 = my0 + 16 * 40;

  // Per-tile folded scale: tiles 0-3 = i,f (sigmoid, -log2e); 4-5 = g (tanh, +2log2e); 6-7 = o
  const float sc_tab[8] = {-LOG2E, -LOG2E, -LOG2E, -LOG2E,
                            2.0f * LOG2E, 2.0f * LOG2E, -LOG2E, -LOG2E};

  // ---- Load weight B-fragments (held in registers for the whole T loop) ----
  // B-frag (K x N = 32 x 16): lane holds B[k = q*8+j][nn = c] = sc * W[tau*16+c][q*8+j]
  bf16x8 wb0[8], wb1[8], wb2[8];
  {
    const float* pW0 = Whh0 + n * (NG * NH);
    const float* pW1 = Wih1 + n * (NG * NH);
    const float* pW2 = Whh1 + n * (NG * NH);
#pragma unroll
    for (int tau = 0; tau < 8; ++tau) {
      int off = (tau * 16 + c) * NH + q * 8;
      float sc = sc_tab[tau];
#pragma unroll
      for (int j = 0; j < 8; ++j) {
        wb0[tau][j] = f2bf(sc * pW0[off + j]);
        wb1[tau][j] = f2bf(sc * pW1[off + j]);
        wb2[tau][j] = f2bf(sc * pW2[off + j]);
      }
    }
  }
  // Per-lane gate constants (scale-folded): g = tau*16 + c
  float b0g[8], b1g[8], wi0g[8];
#pragma unroll
  for (int tau = 0; tau < 8; ++tau) {
    int g = tau * 16 + c;
    float sc = sc_tab[tau];
    b0g[tau]  = sc * b0[n * NG + g];
    b1g[tau]  = sc * b1[n * NG + g];
    wi0g[tau] = sc * Wih0[n * NG + g];   // W_ih0[n, g, 0]
  }
  const float wfc0 = Wfc[n * NH + c];
  const float wfc1 = Wfc[n * NH + 16 + c];

  // x row pointers for the 4 batch rows this lane's quad covers (m = q*4 + r)
  const float* px0 = x + ((size_t)(m0 + q * 4 + 0) * NN + n) * NT;
  const float* px1 = x + ((size_t)(m0 + q * 4 + 1) * NN + n) * NT;
  const float* px2 = x + ((size_t)(m0 + q * 4 + 2) * NN + n) * NT;
  const float* px3 = x + ((size_t)(m0 + q * 4 + 3) * NN + n) * NT;

  // Recurrent state. a0/a1: A-frags of h0/h1 (bf16). c-state & h1 in packed f32x2,
  // indexed [tu][pair] where pair p covers rows {2p, 2p+1}.
  bf16x8 a0 = {0,0,0,0,0,0,0,0};
  bf16x8 a1 = {0,0,0,0,0,0,0,0};
  f32x2 c0p[2][2], c1p[2][2], h1p[2][2];
#pragma unroll
  for (int tu = 0; tu < 2; ++tu)
#pragma unroll
    for (int p = 0; p < 2; ++p) {
      c0p[tu][p] = (f32x2){0.f, 0.f};
      c1p[tu][p] = (f32x2){0.f, 0.f};
      h1p[tu][p] = (f32x2){0.f, 0.f};
    }

#pragma unroll 1
  for (int t4 = 0; t4 < NT / 4; ++t4) {
    // 4 timesteps of x per batch row, vectorized load
    f32v4 xr0 = *(const f32v4*)(px0 + t4 * 4);
    f32v4 xr1 = *(const f32v4*)(px1 + t4 * 4);
    f32v4 xr2 = *(const f32v4*)(px2 + t4 * 4);
    f32v4 xr3 = *(const f32v4*)(px3 + t4 * 4);

#pragma unroll
    for (int ts = 0; ts < 4; ++ts) {
      f32x2 x01 = {xr0[ts], xr1[ts]};
      f32x2 x23 = {xr2[ts], xr3[ts]};

      // ---- Layer 0: gates = (x*Wi0' + b0') + h0_prev @ W_hh0'^T  (packed init) ----
      f32x4 acc[8];
#pragma unroll
      for (int tau = 0; tau < 8; ++tau) {
        f32x2 w2 = {wi0g[tau], wi0g[tau]};
        f32x2 b2 = {b0g[tau], b0g[tau]};
        f32x2 lo = x01 * w2 + b2;   // v_pk_fma_f32
        f32x2 hi = x23 * w2 + b2;
        acc[tau] = (f32x4){lo.x, lo.y, hi.x, hi.y};
      }
#pragma unroll
      for (int tau = 0; tau < 8; ++tau)
        acc[tau] = __builtin_amdgcn_mfma_f32_16x16x32_bf16(a0, wb0[tau], acc[tau], 0, 0, 0);

      // cell update: unit j = tu*16 + c lives at tiles {tu, tu+2, tu+4, tu+6} = {i,f,g,o}
#pragma unroll
      for (int tu = 0; tu < 2; ++tu) {
#pragma unroll
        for (int p = 0; p < 2; ++p) {
          f32x2 gi = { acc[tu    ][2*p], acc[tu    ][2*p+1] };
          f32x2 gf = { acc[tu + 2][2*p], acc[tu + 2][2*p+1] };
          f32x2 gg = { acc[tu + 4][2*p], acc[tu + 4][2*p+1] };
          f32x2 go = { acc[tu + 6][2*p], acc[tu + 6][2*p+1] };
          f32x2 si = sigm2(gi), sf = sigm2(gf), tg = tanh2pre(gg), so = sigm2(go);
          f32x2 cc = sf * c0p[tu][p] + si * tg;
          c0p[tu][p] = cc;
          f32x2 tc = tanh2pre(cc * (2.0f * LOG2E));
          f32x2 hh = so * tc;
          my0[(q * 4 + 2*p    ) * 40 + tu * 16 + c] = f2bf(hh.x);
          my0[(q * 4 + 2*p + 1) * 40 + tu * 16 + c] = f2bf(hh.y);
        }
      }
      asm volatile("" ::: "memory");
      a0 = *(const bf16x8*)(my0 + c * 40 + q * 8);  // A-frag: A[m=c][k=q*8+j]

      // ---- Layer 1: gates = b1' + h0_new @ W_ih1'^T + h1_prev @ W_hh1'^T ----
#pragma unroll
      for (int tau = 0; tau < 8; ++tau) {
        float b = b1g[tau];
        acc[tau] = (f32x4){b, b, b, b};
      }
#pragma unroll
      for (int tau = 0; tau < 8; ++tau)
        acc[tau] = __builtin_amdgcn_mfma_f32_16x16x32_bf16(a0, wb1[tau], acc[tau], 0, 0, 0);
#pragma unroll
      for (int tau = 0; tau < 8; ++tau)
        acc[tau] = __builtin_amdgcn_mfma_f32_16x16x32_bf16(a1, wb2[tau], acc[tau], 0, 0, 0);

#pragma unroll
      for (int tu = 0; tu < 2; ++tu) {
#pragma unroll
        for (int p = 0; p < 2; ++p) {
          f32x2 gi = { acc[tu    ][2*p], acc[tu    ][2*p+1] };
          f32x2 gf = { acc[tu + 2][2*p], acc[tu + 2][2*p+1] };
          f32x2 gg = { acc[tu + 4][2*p], acc[tu + 4][2*p+1] };
          f32x2 go = { acc[tu + 6][2*p], acc[tu + 6][2*p+1] };
          f32x2 si = sigm2(gi), sf = sigm2(gf), tg = tanh2pre(gg), so = sigm2(go);
          f32x2 cc = sf * c1p[tu][p] + si * tg;
          c1p[tu][p] = cc;
          f32x2 tc = tanh2pre(cc * (2.0f * LOG2E));
          f32x2 hh = so * tc;
          h1p[tu][p] = hh;
          my1[(q * 4 + 2*p    ) * 40 + tu * 16 + c] = f2bf(hh.x);
          my1[(q * 4 + 2*p + 1) * 40 + tu * 16 + c] = f2bf(hh.y);
        }
      }
      asm volatile("" ::: "memory");
      a1 = *(const bf16x8*)(my1 + c * 40 + q * 8);
    }
  }

  // ---- Output: out[b, n] = sum_j h1[b][j] * Wfc[n, 0, j] + bfc[n] ----
  // lane holds h1[m = q*4 + 2p+e][j = tu*16 + c]; reduce over the 16 c-lanes of each quad.
  float s0 = h1p[0][0].x * wfc0 + h1p[1][0].x * wfc1;
  float s1 = h1p[0][0].y * wfc0 + h1p[1][0].y * wfc1;
  float s2 = h1p[0][1].x * wfc0 + h1p[1][1].x * wfc1;
  float s3 = h1p[0][1].y * wfc0 + h1p[1][1].y * wfc1;
#pragma unroll
  for (int off = 1; off < 16; off <<= 1) {
    s0 += __shfl_xor(s0, off, 64);
    s1 += __shfl_xor(s1, off, 64);
    s2 += __shfl_xor(s2, off, 64);
    s3 += __shfl_xor(s3, off, 64);
  }
  if (c < 4) {
    float v = (c == 0) ? s0 : (c == 1) ? s1 : (c == 2) ? s2 : s3;
    out[(size_t)(m0 + q * 4 + c) * NN + n] = v + bfc[n];
  }
}

extern "C" void kernel_launch(void* const* d_in, const int* in_sizes, int n_in,
                              void* d_out, int out_size, void* d_ws, size_t ws_size,
                              hipStream_t stream) {
  const float* x    = (const float*)d_in[0];
  const float* Wih0 = (const float*)d_in[1];
  const float* Whh0 = (const float*)d_in[2];
  const float* b0   = (const float*)d_in[3];
  const float* Wih1 = (const float*)d_in[4];
  const float* Whh1 = (const float*)d_in[5];
  const float* b1   = (const float*)d_in[6];
  const float* Wfc  = (const float*)d_in[7];
  const float* bfc  = (const float*)d_in[8];
  float* out = (float*)d_out;

  lstm_kernel<<<dim3(1024), dim3(256), 0, stream>>>(
      x, Wih0, Whh0, b0, Wih1, Whh1, b1, Wfc, bfc, out);
}

// Round 4
// 1294.940 us; speedup vs baseline: 2.3349x; 1.1286x over previous
//
#include <hip/hip_runtime.h>
#include <stdint.h>

#define NB 512   // batch
#define NN 128   // nodes
#define NT 336   // timesteps
#define NH 32    // hidden
#define NG 128   // 4*H

typedef short bf16x8 __attribute__((ext_vector_type(8)));
typedef float f32x4  __attribute__((ext_vector_type(4)));
typedef float f32x2  __attribute__((ext_vector_type(2)));
typedef float f32v4  __attribute__((ext_vector_type(4)));

#define LOG2E 1.4426950408889634f

__device__ __forceinline__ f32x2 exp2v(f32x2 v) {
  f32x2 r; r.x = __builtin_amdgcn_exp2f(v.x); r.y = __builtin_amdgcn_exp2f(v.y); return r;
}
__device__ __forceinline__ f32x2 rcpv(f32x2 v) {
  f32x2 r; r.x = __builtin_amdgcn_rcpf(v.x); r.y = __builtin_amdgcn_rcpf(v.y); return r;
}
// float -> bf16, round-to-nearest (ties away): 1 VALU add, shift folds into b16-hi store
__device__ __forceinline__ short f2bf(float f) {
  unsigned u = __builtin_bit_cast(unsigned, f) + 0x8000u;
  return (short)(u >> 16);
}

// Fused LSTM cell for a pair of batch rows (packed f32x2).
// Inputs are pre-scaled gate values: i,f,o rows scaled by -log2e, g rows by -2log2e
// (scales folded into weights). BIAS=true folds bias multiplicatively: w*e^{b'}.
// sigma(x) = 1/(1+e^{-x}) = 1/A;  tanh(x) = (1-e^{-2x})/(1+e^{-2x}).
// c' = [c*Ai*Au + (1-u)*Af] / (Af*Ai*Au)   -- single rcp
// h  = (1-v) / (Ao*(1+v)),  v = e^{-2c'}    -- single rcp
template<bool BIAS>
__device__ __forceinline__ f32x2 cell_pair(f32x2 gi, f32x2 gf, f32x2 gg, f32x2 go,
                                           f32x2& cst, float ebi, float ebf,
                                           float ebg, float ebo) {
  f32x2 wi = exp2v(gi), wf = exp2v(gf), uu = exp2v(gg), wo = exp2v(go);
  f32x2 Ai, Af, Au, Ao, nu;
  if (BIAS) {
    Ai = wi * ebi + 1.0f;          // v_pk_fma_f32
    Af = wf * ebf + 1.0f;
    Au = uu * ebg + 1.0f;
    Ao = wo * ebo + 1.0f;
    nu = 1.0f - uu * ebg;
  } else {
    Ai = wi + 1.0f; Af = wf + 1.0f; Au = uu + 1.0f; Ao = wo + 1.0f;
    nu = 1.0f - uu;
  }
  f32x2 P  = Ai * Au;
  f32x2 N  = cst * P + nu * Af;
  f32x2 cn = N * rcpv(Af * P);
  cst = cn;
  f32x2 sarg = cn * (-2.0f * LOG2E);
  // guard: c very negative -> v=inf -> inf/inf NaN. Clamped value still gives -sigma(o).
  sarg.x = fminf(sarg.x, 80.0f);
  sarg.y = fminf(sarg.y, 80.0f);
  f32x2 vv = exp2v(sarg);
  f32x2 hh = (1.0f - vv) * rcpv(Ao * (vv + 1.0f));
  return hh;
}

// One wave handles (node n, 16 batch rows). Block = 4 waves = 64 rows of one node.
// Grid = 128 nodes * 8 row-groups = 1024 blocks.
__global__ __launch_bounds__(256, 2) void lstm_kernel(
    const float* __restrict__ x,
    const float* __restrict__ Wih0,
    const float* __restrict__ Whh0,
    const float* __restrict__ b0,
    const float* __restrict__ Wih1,
    const float* __restrict__ Whh1,
    const float* __restrict__ b1,
    const float* __restrict__ Wfc,
    const float* __restrict__ bfc,
    float* __restrict__ out)
{
  const int tid  = threadIdx.x;
  const int wave = tid >> 6;
  const int lane = tid & 63;
  const int c    = lane & 15;   // tile column (gate-within-tile / A-row)
  const int q    = lane >> 4;   // quad
  const int n    = blockIdx.x >> 3;
  const int m0   = ((blockIdx.x & 7) * 4 + wave) * 16;  // batch row base of this wave

  // Per-wave private LDS: 2 buffers of 16 rows x 40 bf16 (stride 40 -> 80B rows,
  // 16B-aligned b128 reads). No cross-wave sharing -> no barriers.
  __shared__ short lds[4 * 2 * 16 * 40];
  short* my0 = lds + wave * (2 * 16 * 40);
  short* my1 = my0 + 16 * 40;

  // Per-tile folded scale: tiles 0-3 = i,f (sigmoid, -log2e); 4-5 = g (tanh, -2log2e);
  // 6-7 = o (sigmoid, -log2e).
  const float sc_tab[8] = {-LOG2E, -LOG2E, -LOG2E, -LOG2E,
                           -2.0f * LOG2E, -2.0f * LOG2E, -LOG2E, -LOG2E};

  // ---- Load weight B-fragments (held in registers for the whole T loop) ----
  // B-frag (K x N = 32 x 16): lane holds B[k = q*8+j][nn = c] = sc * W[tau*16+c][q*8+j]
  bf16x8 wb0[8], wb1[8], wb2[8];
  {
    const float* pW0 = Whh0 + n * (NG * NH);
    const float* pW1 = Wih1 + n * (NG * NH);
    const float* pW2 = Whh1 + n * (NG * NH);
#pragma unroll
    for (int tau = 0; tau < 8; ++tau) {
      int off = (tau * 16 + c) * NH + q * 8;
      float sc = sc_tab[tau];
#pragma unroll
      for (int j = 0; j < 8; ++j) {
        wb0[tau][j] = f2bf(sc * pW0[off + j]);
        wb1[tau][j] = f2bf(sc * pW1[off + j]);
        wb2[tau][j] = f2bf(sc * pW2[off + j]);
      }
    }
  }
  // Per-lane gate constants: g = tau*16 + c.
  // Layer 0: additive (folded into MFMA C init). Layer 1: multiplicative e^{sc*b}.
  float b0g[8], eb1[8], wi0g[8];
#pragma unroll
  for (int tau = 0; tau < 8; ++tau) {
    int g = tau * 16 + c;
    float sc = sc_tab[tau];
    b0g[tau]  = sc * b0[n * NG + g];
    eb1[tau]  = __builtin_amdgcn_exp2f(sc * b1[n * NG + g]);
    wi0g[tau] = sc * Wih0[n * NG + g];   // W_ih0[n, g, 0]
  }
  const float wfc0 = Wfc[n * NH + c];
  const float wfc1 = Wfc[n * NH + 16 + c];

  // x row pointers for the 4 batch rows this lane's quad covers (m = q*4 + r)
  const float* px0 = x + ((size_t)(m0 + q * 4 + 0) * NN + n) * NT;
  const float* px1 = x + ((size_t)(m0 + q * 4 + 1) * NN + n) * NT;
  const float* px2 = x + ((size_t)(m0 + q * 4 + 2) * NN + n) * NT;
  const float* px3 = x + ((size_t)(m0 + q * 4 + 3) * NN + n) * NT;

  // Recurrent state. a0/a1: A-frags of h0/h1 (bf16). c-state & h1 in packed f32x2,
  // indexed [tu][pair] where pair p covers rows {2p, 2p+1}.
  bf16x8 a0 = {0,0,0,0,0,0,0,0};
  bf16x8 a1 = {0,0,0,0,0,0,0,0};
  f32x2 c0p[2][2], c1p[2][2], h1p[2][2];
#pragma unroll
  for (int tu = 0; tu < 2; ++tu)
#pragma unroll
    for (int p = 0; p < 2; ++p) {
      c0p[tu][p] = (f32x2){0.f, 0.f};
      c1p[tu][p] = (f32x2){0.f, 0.f};
      h1p[tu][p] = (f32x2){0.f, 0.f};
    }

  const f32x4 zero4 = {0.f, 0.f, 0.f, 0.f};  // shared MFMA C for layer-1 init

#pragma unroll 1
  for (int t4 = 0; t4 < NT / 4; ++t4) {
    // 4 timesteps of x per batch row, vectorized load
    f32v4 xr0 = *(const f32v4*)(px0 + t4 * 4);
    f32v4 xr1 = *(const f32v4*)(px1 + t4 * 4);
    f32v4 xr2 = *(const f32v4*)(px2 + t4 * 4);
    f32v4 xr3 = *(const f32v4*)(px3 + t4 * 4);

#pragma unroll
    for (int ts = 0; ts < 4; ++ts) {
      f32x2 x01 = {xr0[ts], xr1[ts]};
      f32x2 x23 = {xr2[ts], xr3[ts]};

      // ---- Layer 0: gates' = sc*(x*Wi0 + b0) + h0_prev @ (sc*W_hh0)^T ----
      f32x4 acc[8];
#pragma unroll
      for (int tau = 0; tau < 8; ++tau) {
        f32x2 w2 = {wi0g[tau], wi0g[tau]};
        f32x2 b2 = {b0g[tau], b0g[tau]};
        f32x2 lo = x01 * w2 + b2;   // v_pk_fma_f32
        f32x2 hi = x23 * w2 + b2;
        acc[tau] = (f32x4){lo.x, lo.y, hi.x, hi.y};
      }
#pragma unroll
      for (int tau = 0; tau < 8; ++tau)
        acc[tau] = __builtin_amdgcn_mfma_f32_16x16x32_bf16(a0, wb0[tau], acc[tau], 0, 0, 0);

      // cell update: unit j = tu*16 + c lives at tiles {tu, tu+2, tu+4, tu+6} = {i,f,g,o}
#pragma unroll
      for (int tu = 0; tu < 2; ++tu) {
#pragma unroll
        for (int p = 0; p < 2; ++p) {
          f32x2 gi = { acc[tu    ][2*p], acc[tu    ][2*p+1] };
          f32x2 gf = { acc[tu + 2][2*p], acc[tu + 2][2*p+1] };
          f32x2 gg = { acc[tu + 4][2*p], acc[tu + 4][2*p+1] };
          f32x2 go = { acc[tu + 6][2*p], acc[tu + 6][2*p+1] };
          f32x2 hh = cell_pair<false>(gi, gf, gg, go, c0p[tu][p], 1.f, 1.f, 1.f, 1.f);
          my0[(q * 4 + 2*p    ) * 40 + tu * 16 + c] = f2bf(hh.x);
          my0[(q * 4 + 2*p + 1) * 40 + tu * 16 + c] = f2bf(hh.y);
        }
      }
      asm volatile("" ::: "memory");
      a0 = *(const bf16x8*)(my0 + c * 40 + q * 8);  // A-frag: A[m=c][k=q*8+j]

      // ---- Layer 1: gates' = sc*b1 (mult-folded) + h0_new @ W' + h1_prev @ W'' ----
#pragma unroll
      for (int tau = 0; tau < 8; ++tau)
        acc[tau] = __builtin_amdgcn_mfma_f32_16x16x32_bf16(a0, wb1[tau], zero4, 0, 0, 0);
#pragma unroll
      for (int tau = 0; tau < 8; ++tau)
        acc[tau] = __builtin_amdgcn_mfma_f32_16x16x32_bf16(a1, wb2[tau], acc[tau], 0, 0, 0);

#pragma unroll
      for (int tu = 0; tu < 2; ++tu) {
#pragma unroll
        for (int p = 0; p < 2; ++p) {
          f32x2 gi = { acc[tu    ][2*p], acc[tu    ][2*p+1] };
          f32x2 gf = { acc[tu + 2][2*p], acc[tu + 2][2*p+1] };
          f32x2 gg = { acc[tu + 4][2*p], acc[tu + 4][2*p+1] };
          f32x2 go = { acc[tu + 6][2*p], acc[tu + 6][2*p+1] };
          f32x2 hh = cell_pair<true>(gi, gf, gg, go, c1p[tu][p],
                                     eb1[tu], eb1[tu + 2], eb1[tu + 4], eb1[tu + 6]);
          h1p[tu][p] = hh;
          my1[(q * 4 + 2*p    ) * 40 + tu * 16 + c] = f2bf(hh.x);
          my1[(q * 4 + 2*p + 1) * 40 + tu * 16 + c] = f2bf(hh.y);
        }
      }
      asm volatile("" ::: "memory");
      a1 = *(const bf16x8*)(my1 + c * 40 + q * 8);
    }
  }

  // ---- Output: out[b, n] = sum_j h1[b][j] * Wfc[n, 0, j] + bfc[n] ----
  // lane holds h1[m = q*4 + 2p+e][j = tu*16 + c]; reduce over the 16 c-lanes of each quad.
  float s0 = h1p[0][0].x * wfc0 + h1p[1][0].x * wfc1;
  float s1 = h1p[0][0].y * wfc0 + h1p[1][0].y * wfc1;
  float s2 = h1p[0][1].x * wfc0 + h1p[1][1].x * wfc1;
  float s3 = h1p[0][1].y * wfc0 + h1p[1][1].y * wfc1;
#pragma unroll
  for (int off = 1; off < 16; off <<= 1) {
    s0 += __shfl_xor(s0, off, 64);
    s1 += __shfl_xor(s1, off, 64);
    s2 += __shfl_xor(s2, off, 64);
    s3 += __shfl_xor(s3, off, 64);
  }
  if (c < 4) {
    float v = (c == 0) ? s0 : (c == 1) ? s1 : (c == 2) ? s2 : s3;
    out[(size_t)(m0 + q * 4 + c) * NN + n] = v + bfc[n];
  }
}

extern "C" void kernel_launch(void* const* d_in, const int* in_sizes, int n_in,
                              void* d_out, int out_size, void* d_ws, size_t ws_size,
                              hipStream_t stream) {
  const float* x    = (const float*)d_in[0];
  const float* Wih0 = (const float*)d_in[1];
  const float* Whh0 = (const float*)d_in[2];
  const float* b0   = (const float*)d_in[3];
  const float* Wih1 = (const float*)d_in[4];
  const float* Whh1 = (const float*)d_in[5];
  const float* b1   = (const float*)d_in[6];
  const float* Wfc  = (const float*)d_in[7];
  const float* bfc  = (const float*)d_in[8];
  float* out = (float*)d_out;

  lstm_kernel<<<dim3(1024), dim3(256), 0, stream>>>(
      x, Wih0, Whh0, b0, Wih1, Whh1, b1, Wfc, bfc, out);
}